// Round 4
// baseline (2062.188 us; speedup 1.0000x reference)
//
#include <hip/hip_runtime.h>

#define N_TOK 8192
#define C_DIM 2048
#define F_DIM 5632
#define E_NUM 8
#define BK 64

#define BM 256
#define MAXT 72                      // sum ceil(cnt_e/256) <= 16384/256 + 8 = 72
#define BN1 128
#define GRID1 (MAXT * (F_DIM/BN1))   // 72*44 = 3168, /8 = 396
#define BN2 128
#define GRID2 (MAXT * (C_DIM/BN2))   // 72*16 = 1152, /8 = 144
#define NT1 (C_DIM/BK)               // 32
#define NT2 (F_DIM/BK)               // 88

typedef __attribute__((ext_vector_type(8))) short bf16x8;
typedef __attribute__((ext_vector_type(4))) float f32x4;

typedef const void __attribute__((address_space(1)))* gas1;
typedef void __attribute__((address_space(3)))* las3;

__device__ __forceinline__ unsigned short f2bf(float f){
  union { float f; unsigned u; } v; v.f = f;
  unsigned r = v.u + 0x7FFFu + ((v.u >> 16) & 1u);   // RNE
  return (unsigned short)(r >> 16);
}

__device__ __forceinline__ unsigned pkbf(float a, float b){
  unsigned r;
  asm("v_cvt_pk_bf16_f32 %0, %1, %2" : "=v"(r) : "v"(a), "v"(b));
  return r;   // lo16 = bf(a), hi16 = bf(b)
}

__device__ __forceinline__ void glds16(const unsigned short* g, unsigned short* l){
  __builtin_amdgcn_global_load_lds((gas1)g, (las3)l, 16, 0, 0);
}

#define MFMA_BF16 __builtin_amdgcn_mfma_f32_16x16x32_bf16
#define HSW(v) ((((v) >> 1) ^ ((v) >> 2)) & 7)

// ---------------- x fp32 -> bf16 ----------------
__global__ void k_cvt_x(const float* __restrict__ x, unsigned short* __restrict__ xb, int n4){
  int i = blockIdx.x * blockDim.x + threadIdx.x;
  int stride = gridDim.x * blockDim.x;
  const float4* xi = (const float4*)x;
  ushort4* xo = (ushort4*)xb;
  for (; i < n4; i += stride){
    float4 v = xi[i];
    ushort4 o; o.x = f2bf(v.x); o.y = f2bf(v.y); o.z = f2bf(v.z); o.w = f2bf(v.w);
    xo[i] = o;
  }
}

// ------- weight convert + transpose (W1/W3 only): [R][Cc] fp32 -> [Cc][R] bf16 -------
__global__ void k_tcvt_w(const float* __restrict__ in, unsigned short* __restrict__ out, int R, int Cc){
  __shared__ float t[64][65];
  size_t slab = (size_t)blockIdx.z * R * Cc;
  in += slab; out += slab;
  int c0 = blockIdx.x * 64, r0 = blockIdx.y * 64;
  int tx = threadIdx.x, ty = threadIdx.y;     // 64 x 4
  #pragma unroll
  for (int i = 0; i < 16; ++i){
    int r = ty + i*4;
    t[r][tx] = in[(size_t)(r0 + r) * Cc + c0 + tx];
  }
  __syncthreads();
  #pragma unroll
  for (int i = 0; i < 16; ++i){
    int cr = ty + i*4;
    out[(size_t)(c0 + cr) * R + r0 + tx] = f2bf(t[tx][cr]);
  }
}

// ---------------- router ----------------
__global__ void k_router(const float* __restrict__ x, const float* __restrict__ Wg,
                         int* __restrict__ cnt, int* __restrict__ list, float* __restrict__ p_slot)
{
  int wid = threadIdx.x >> 6, lane = threadIdx.x & 63;
  int n = blockIdx.x * 4 + wid;                 // one wave per token
  int e = lane >> 3, sub = lane & 7;
  const float* xr = x + (size_t)n * C_DIM;
  float acc = 0.f;
  for (int i0 = sub*4; i0 < C_DIM; i0 += 32){
    float4 v = *(const float4*)&xr[i0];
    acc += v.x * Wg[(i0  )*E_NUM + e];
    acc += v.y * Wg[(i0+1)*E_NUM + e];
    acc += v.z * Wg[(i0+2)*E_NUM + e];
    acc += v.w * Wg[(i0+3)*E_NUM + e];
  }
  acc += __shfl_xor(acc, 1);
  acc += __shfl_xor(acc, 2);
  acc += __shfl_xor(acc, 4);
  float lg[E_NUM];
  #pragma unroll
  for (int j = 0; j < E_NUM; ++j) lg[j] = __shfl(acc, j*8);
  if (lane == 0){
    int e1 = 0; float m1 = lg[0];
    #pragma unroll
    for (int j = 1; j < E_NUM; ++j) if (lg[j] > m1){ m1 = lg[j]; e1 = j; }
    int e2 = -1; float m2 = -1e30f;
    #pragma unroll
    for (int j = 0; j < E_NUM; ++j) if (j != e1 && lg[j] > m2){ m2 = lg[j]; e2 = j; }
    float p1 = 1.f / (1.f + __expf(m2 - m1));
    float p2 = 1.f - p1;
    int pos1 = atomicAdd(&cnt[e1], 1);
    list[e1*N_TOK + pos1] = n*2;
    p_slot[n*2] = p1;
    int pos2 = atomicAdd(&cnt[e2], 1);
    list[e2*N_TOK + pos2] = n*2 + 1;
    p_slot[n*2 + 1] = p2;
  }
}

// ---------------- prefix / tile table ----------------
__global__ void k_prefix(const int* __restrict__ cnt, int* __restrict__ meta){
  if (threadIdx.x == 0 && blockIdx.x == 0){
    int acc = 0, t = 0;
    for (int e = 0; e < E_NUM; ++e){
      meta[e] = acc; acc += cnt[e];
      int nt = (cnt[e] + BM - 1) / BM;
      for (int i = 0; i < nt; ++i) meta[16 + t++] = (e << 16) | i;
    }
    meta[8] = t;
  }
}

#define PHASE_ENTER() do{ __builtin_amdgcn_sched_barrier(0); __builtin_amdgcn_s_barrier(); \
                          __builtin_amdgcn_s_setprio(1); } while(0)
#define PHASE_EXIT()  do{ __builtin_amdgcn_s_setprio(0); __builtin_amdgcn_sched_barrier(0); \
                          __builtin_amdgcn_s_barrier(); } while(0)

// ---------------- GEMM1: 256x128 dual-B 8-phase, h = silu(x@W1)*(x@W3) ----------------
// (unchanged from round 3 — stable anchor)
__global__ __launch_bounds__(512, 2) void k_gemm1(
    const unsigned short* __restrict__ xb,
    const unsigned short* __restrict__ wb1,   // [E][F][C] bf16
    const unsigned short* __restrict__ wb3,   // [E][F][C]
    unsigned short* __restrict__ h,           // [2N+1024][F] bf16
    const int* __restrict__ cnt,
    const int* __restrict__ meta,
    const int* __restrict__ list)
{
  int o = blockIdx.x;
  int w = (o & 7) * (GRID1/8) + (o >> 3);
  int t = w % MAXT;
  int n0 = (w / MAXT) * BN1;
  if (t >= meta[8]) return;
  int info = meta[16 + t];
  int e  = info >> 16;
  int m0 = (info & 0xffff) * BM;
  int count = cnt[e];
  int hbase = meta[e];

  __shared__ __align__(16) unsigned short lds[2*32768];

  int tid = threadIdx.x;
  int lane = tid & 63, wid = tid >> 6;
  int wm = wid >> 1, wn = wid & 1;
  int l15 = lane & 15;
  int xc0 = (lane >> 4) ^ (lane & 7);
  int xc1 = xc0 ^ 4;

  int srow = tid >> 3;
  int swz = ((tid & 7) ^ (srow & 7)) * 8;
  const unsigned short* aP[4];
  #pragma unroll
  for (int u = 0; u < 4; ++u){
    int ts = list[e*N_TOK + m0 + u*64 + srow];
    int tok = (ts >> 1) & (N_TOK - 1);
    aP[u] = xb + (size_t)tok * C_DIM + swz;
  }
  const unsigned short* bP[4];
  #pragma unroll
  for (int u = 0; u < 4; ++u){
    const unsigned short* base = (u < 2) ? wb1 : wb3;
    bP[u] = base + ((size_t)e*F_DIM + n0 + (u & 1)*64 + srow) * C_DIM + swz;
  }
  int ldw = wid * 512;

  #define ST_A(u, kt) glds16(aP[u] + (kt)*BK, &lds[((kt)&1)*32768 + (u)*4096 + ldw])
  #define ST_B(u, kt) glds16(bP[u] + (kt)*BK, &lds[((kt)&1)*32768 + 16384 + (u)*4096 + ldw])

  ST_A(0,0); ST_A(1,0); ST_A(2,0); ST_A(3,0);
  ST_B(0,0); ST_B(1,0); ST_B(2,0); ST_B(3,0);
  ST_A(0,1); ST_A(1,1); ST_A(2,1); ST_A(3,1);
  asm volatile("s_waitcnt vmcnt(4)" ::: "memory");
  __builtin_amdgcn_sched_barrier(0);
  __builtin_amdgcn_s_barrier();

  f32x4 zero = {0.f, 0.f, 0.f, 0.f};
  f32x4 acc1[4][4], acc3[4][4];
  #pragma unroll
  for (int m = 0; m < 4; ++m)
    #pragma unroll
    for (int q = 0; q < 4; ++q){ acc1[m][q] = zero; acc3[m][q] = zero; }

  for (int kt = 0; kt < NT1; ++kt){
    const unsigned short* bufc = &lds[(kt & 1)*32768];
    bf16x8 a[4][2], b1f[2], b3f[2];
    #pragma unroll
    for (int m = 0; m < 4; ++m){
      int row = wm*64 + m*16 + l15;
      a[m][0] = *(const bf16x8*)&bufc[row*64 + xc0*8];
      a[m][1] = *(const bf16x8*)&bufc[row*64 + xc1*8];
    }
    {
      int brow = wn*64 + l15;
      b1f[0] = *(const bf16x8*)&bufc[16384 + brow*64 + xc0*8];
      b1f[1] = *(const bf16x8*)&bufc[16384 + brow*64 + xc1*8];
      b3f[0] = *(const bf16x8*)&bufc[24576 + brow*64 + xc0*8];
      b3f[1] = *(const bf16x8*)&bufc[24576 + brow*64 + xc1*8];
    }
    ST_B(0, kt+1); ST_B(1, kt+1); ST_B(2, kt+1); ST_B(3, kt+1);
    PHASE_ENTER();
    #pragma unroll
    for (int m = 0; m < 4; ++m){
      acc1[m][0] = MFMA_BF16(a[m][0], b1f[0], acc1[m][0], 0, 0, 0);
      acc1[m][0] = MFMA_BF16(a[m][1], b1f[1], acc1[m][0], 0, 0, 0);
      acc3[m][0] = MFMA_BF16(a[m][0], b3f[0], acc3[m][0], 0, 0, 0);
      acc3[m][0] = MFMA_BF16(a[m][1], b3f[1], acc3[m][0], 0, 0, 0);
    }
    PHASE_EXIT();
    #pragma unroll
    for (int q = 1; q < 4; ++q){
      int brow = wn*64 + q*16 + l15;
      b1f[0] = *(const bf16x8*)&bufc[16384 + brow*64 + xc0*8];
      b1f[1] = *(const bf16x8*)&bufc[16384 + brow*64 + xc1*8];
      b3f[0] = *(const bf16x8*)&bufc[24576 + brow*64 + xc0*8];
      b3f[1] = *(const bf16x8*)&bufc[24576 + brow*64 + xc1*8];
      if (q == 1){ ST_A(0, kt+2); ST_A(1, kt+2); }
      if (q == 2){ ST_A(2, kt+2); ST_A(3, kt+2); }
      PHASE_ENTER();
      #pragma unroll
      for (int m = 0; m < 4; ++m){
        acc1[m][q] = MFMA_BF16(a[m][0], b1f[0], acc1[m][q], 0, 0, 0);
        acc1[m][q] = MFMA_BF16(a[m][1], b1f[1], acc1[m][q], 0, 0, 0);
        acc3[m][q] = MFMA_BF16(a[m][0], b3f[0], acc3[m][q], 0, 0, 0);
        acc3[m][q] = MFMA_BF16(a[m][1], b3f[1], acc3[m][q], 0, 0, 0);
      }
      __builtin_amdgcn_s_setprio(0);
      if (q == 3) asm volatile("s_waitcnt vmcnt(4)" ::: "memory");
      __builtin_amdgcn_sched_barrier(0);
      __builtin_amdgcn_s_barrier();
    }
  }
  asm volatile("s_waitcnt vmcnt(0)" ::: "memory");

  #pragma unroll
  for (int m = 0; m < 4; ++m){
    #pragma unroll
    for (int r = 0; r < 4; ++r){
      int rloc = m0 + wm*64 + m*16 + ((lane >> 4) * 4) + r;
      if (rloc < count){
        unsigned short* hrow = h + (size_t)(hbase + rloc) * F_DIM + n0 + wn*64 + l15;
        #pragma unroll
        for (int q = 0; q < 4; ++q){
          float v1 = acc1[m][q][r];
          float v3 = acc3[m][q][r];
          float hv = (v1 / (1.f + __expf(-v1))) * v3;
          hrow[q*16] = f2bf(hv);
        }
      }
    }
  }
  #undef ST_A
  #undef ST_B
}

// ---------------- GEMM2: 256x128, direct-fp32 W2 (in-kernel transpose), 2 phases/kt ----------------
__global__ __launch_bounds__(512, 2) void k_gemm2(
    const unsigned short* __restrict__ h,
    const float* __restrict__ W2,             // [E][F][C] fp32 (original layout)
    float* __restrict__ y,                    // [N][C] fp32, pre-zeroed
    const int* __restrict__ cnt,
    const int* __restrict__ meta,
    const int* __restrict__ list,
    const float* __restrict__ p_slot)
{
  int o = blockIdx.x;
  int w = (o & 7) * (GRID2/8) + (o >> 3);
  int t = w % MAXT;
  int n0 = (w / MAXT) * BN2;
  if (t >= meta[8]) return;
  int info = meta[16 + t];
  int e  = info >> 16;
  int m0 = (info & 0xffff) * BM;
  int count = cnt[e];
  int hbase = meta[e];

  // per buffer: A[256][64] bf16 (16384 el) + B[128][64] bf16 (8192 el) = 24576 el; x2 = 96 KiB
  __shared__ __align__(16) unsigned short lds[2*24576];

  int tid = threadIdx.x;
  int lane = tid & 63, wid = tid >> 6;
  int wm = wid >> 1, wn = wid & 1;            // 4M x 2N waves, wave tile 64x64
  int l15 = lane & 15;
  int xcA0 = (lane >> 4) ^ (lane & 7);
  int xcA1 = xcA0 ^ 4;

  // A staging: h bf16 via global_load_lds (linear dest, pre-swizzled source)
  int srow = tid >> 3;
  int swz = ((tid & 7) ^ (srow & 7)) * 8;
  const unsigned short* aP[4];
  #pragma unroll
  for (int u = 0; u < 4; ++u)
    aP[u] = h + (size_t)(hbase + m0 + u*64 + srow) * F_DIM + swz;
  int ldw = wid * 512;
  #define ST_A2(u, kt2) glds16(aP[u] + (kt2)*BK, &lds[((kt2)&1)*24576 + (u)*4096 + ldw])

  // B reg-staging: W2 fp32 rows f (k-dim), cols c; transpose to LDS B[c][64 f-elems]
  int fT = (tid >> 5) * 4;                    // 0..60: k-rows owned
  int cT = (tid & 31) * 4;                    // 0..124: c-cols owned
  const float* wG = W2 + ((size_t)e * F_DIM + fT) * C_DIM + n0 + cT;
  int fb7 = fT & 7, fb3 = fT >> 3;

  #define LOADW(V, kk) do{ _Pragma("unroll") for (int r_ = 0; r_ < 4; ++r_) \
      V[r_] = *(const float4*)(wG + (size_t)((kk)*64 + r_) * C_DIM); }while(0)
  // write (c = cT+i): elems [c*64 + ((fb3 ^ HSW(c))*8) + fb7 .. +3] = f=fT..fT+3 at col c
  #define CVTW(V, pb) do{ unsigned short* bb_ = &lds[(pb)*24576 + 16384]; \
      _Pragma("unroll") for (int i_ = 0; i_ < 4; ++i_){ \
        int c_ = cT + i_; uint2 u_; \
        u_.x = pkbf(((const float*)&V[0])[i_], ((const float*)&V[1])[i_]); \
        u_.y = pkbf(((const float*)&V[2])[i_], ((const float*)&V[3])[i_]); \
        *(uint2*)&bb_[c_*64 + ((fb3 ^ HSW(c_))*8) + fb7] = u_; } }while(0)

  // B-frag read precompute (kt-invariant)
  int bch[4], brow[4];
  #pragma unroll
  for (int q = 0; q < 4; ++q){
    int cr = wn*64 + q*16 + l15;
    bch[q] = HSW(cr); brow[q] = cr*64;
  }

  f32x4 zero = {0.f, 0.f, 0.f, 0.f};
  f32x4 acc[4][4];
  #pragma unroll
  for (int m = 0; m < 4; ++m)
    #pragma unroll
    for (int q = 0; q < 4; ++q) acc[m][q] = zero;

  // prologue: W(0) regs; A(0),A(1) gloads; cvt W(0)->buf0; load W(1) hold; drain A(0)
  float4 wv[4], wx[4];
  LOADW(wv, 0);
  #pragma unroll
  for (int u = 0; u < 4; ++u) ST_A2(u, 0);
  #pragma unroll
  for (int u = 0; u < 4; ++u) ST_A2(u, 1);
  CVTW(wv, 0);
  LOADW(wv, 1);
  asm volatile("s_waitcnt vmcnt(8)" ::: "memory");   // A(0) landed
  asm volatile("s_waitcnt lgkmcnt(0)" ::: "memory");
  __builtin_amdgcn_sched_barrier(0);
  __builtin_amdgcn_s_barrier();

  for (int kt = 0; kt < NT2; ++kt){
    const unsigned short* bufc = &lds[(kt & 1)*24576];
    int k2 = (kt + 2 < NT2) ? kt + 2 : NT2 - 1;
    bf16x8 a[4][2], bf[2][2];
    // ---- phase 0: issue W(kt+2); read A-frags + B q0,q1; cvt+write W(kt+1); MFMA q0,q1 ----
    LOADW(wx, k2);
    #pragma unroll
    for (int m = 0; m < 4; ++m){
      int row = wm*64 + m*16 + l15;
      a[m][0] = *(const bf16x8*)&bufc[row*64 + xcA0*8];
      a[m][1] = *(const bf16x8*)&bufc[row*64 + xcA1*8];
    }
    #pragma unroll
    for (int j = 0; j < 2; ++j){
      bf[j][0] = *(const bf16x8*)&bufc[16384 + brow[j] + (((lane>>4)    ) ^ bch[j])*8];
      bf[j][1] = *(const bf16x8*)&bufc[16384 + brow[j] + (((lane>>4) + 4) ^ bch[j])*8];
    }
    CVTW(wv, (kt+1)&1);
    PHASE_ENTER();
    #pragma unroll
    for (int m = 0; m < 4; ++m)
      #pragma unroll
      for (int j = 0; j < 2; ++j){
        acc[m][j] = MFMA_BF16(a[m][0], bf[j][0], acc[m][j], 0, 0, 0);
        acc[m][j] = MFMA_BF16(a[m][1], bf[j][1], acc[m][j], 0, 0, 0);
      }
    PHASE_EXIT();
    // ---- phase 1: issue A(kt+2); read B q2,q3; drain A(kt+1); MFMA q2,q3 ----
    #pragma unroll
    for (int u = 0; u < 4; ++u) ST_A2(u, kt+2);
    #pragma unroll
    for (int j = 0; j < 2; ++j){
      bf[j][0] = *(const bf16x8*)&bufc[16384 + brow[2+j] + (((lane>>4)    ) ^ bch[2+j])*8];
      bf[j][1] = *(const bf16x8*)&bufc[16384 + brow[2+j] + (((lane>>4) + 4) ^ bch[2+j])*8];
    }
    asm volatile("s_waitcnt vmcnt(8)" ::: "memory");   // A(kt+1) landed (8 younger: wx4 + Anew4)
    PHASE_ENTER();
    #pragma unroll
    for (int m = 0; m < 4; ++m)
      #pragma unroll
      for (int j = 0; j < 2; ++j){
        acc[m][2+j] = MFMA_BF16(a[m][0], bf[j][0], acc[m][2+j], 0, 0, 0);
        acc[m][2+j] = MFMA_BF16(a[m][1], bf[j][1], acc[m][2+j], 0, 0, 0);
      }
    __builtin_amdgcn_s_setprio(0);
    asm volatile("s_waitcnt lgkmcnt(0)" ::: "memory");  // drain B ds_writes before exit barrier
    __builtin_amdgcn_sched_barrier(0);
    __builtin_amdgcn_s_barrier();
    #pragma unroll
    for (int r = 0; r < 4; ++r) wv[r] = wx[r];
  }
  asm volatile("s_waitcnt vmcnt(0)" ::: "memory");

  // epilogue: two commutative fp32 adds per y element from exact 0 -> deterministic
  #pragma unroll
  for (int m = 0; m < 4; ++m){
    #pragma unroll
    for (int r = 0; r < 4; ++r){
      int rloc = m0 + wm*64 + m*16 + ((lane >> 4) * 4) + r;
      if (rloc < count){
        int ts = list[e*N_TOK + rloc];
        float p = p_slot[ts];
        int tok = ts >> 1;
        float* yr = y + (size_t)tok * C_DIM + n0 + wn*64 + l15;
        #pragma unroll
        for (int q = 0; q < 4; ++q)
          atomicAdd(&yr[q*16], p * acc[m][q][r]);
      }
    }
  }
  #undef ST_A2
  #undef LOADW
  #undef CVTW
}

extern "C" void kernel_launch(void* const* d_in, const int* in_sizes, int n_in,
                              void* d_out, int out_size, void* d_ws, size_t ws_size,
                              hipStream_t stream)
{
  const float* x  = (const float*)d_in[0];
  const float* Wg = (const float*)d_in[1];
  const float* W1 = (const float*)d_in[2];
  const float* W3 = (const float*)d_in[3];
  const float* W2 = (const float*)d_in[4];
  float* y = (float*)d_out;
  (void)in_sizes; (void)n_in; (void)out_size; (void)ws_size;

  char* ws = (char*)d_ws;
  size_t o = 0;
  auto alloc = [&](size_t bytes)->char* {
    char* p = ws + o;
    o = (o + bytes + 255) & ~(size_t)255;
    return p;
  };
  int*    cnt    = (int*)  alloc(E_NUM * 4);
  int*    meta   = (int*)  alloc(160 * 4);
  float*  p_slot = (float*)alloc((size_t)2*N_TOK * 4);
  int*    list   = (int*)  alloc((size_t)E_NUM*N_TOK * 4);
  unsigned short* xb  = (unsigned short*)alloc((size_t)N_TOK*C_DIM * 2);
  unsigned short* wb1 = (unsigned short*)alloc((size_t)E_NUM*C_DIM*F_DIM * 2);
  unsigned short* wb3 = (unsigned short*)alloc((size_t)E_NUM*C_DIM*F_DIM * 2);
  unsigned short* h   = (unsigned short*)alloc((size_t)(2*N_TOK + 1024)*F_DIM * 2);

  hipMemsetAsync(cnt, 0, E_NUM * 4, stream);
  hipMemsetAsync(y, 0, (size_t)N_TOK * C_DIM * 4, stream);
  k_cvt_x<<<4096, 256, 0, stream>>>(x, xb, (N_TOK*C_DIM)/4);
  // W1,W3: [E][C][F] -> [E][F][C] bf16 (W2 now consumed directly by k_gemm2)
  k_tcvt_w<<<dim3(F_DIM/64, C_DIM/64, E_NUM), dim3(64,4), 0, stream>>>(W1, wb1, C_DIM, F_DIM);
  k_tcvt_w<<<dim3(F_DIM/64, C_DIM/64, E_NUM), dim3(64,4), 0, stream>>>(W3, wb3, C_DIM, F_DIM);
  k_router<<<N_TOK/4, 256, 0, stream>>>(x, Wg, cnt, list, p_slot);
  k_prefix<<<1, 64, 0, stream>>>(cnt, meta);
  k_gemm1<<<GRID1, 512, 0, stream>>>(xb, wb1, wb3, h, cnt, meta, list);
  k_gemm2<<<GRID2, 512, 0, stream>>>(h, W2, y, cnt, meta, list, p_slot);
}

// Round 5
// 1833.541 us; speedup vs baseline: 1.1247x; 1.1247x over previous
//
#include <hip/hip_runtime.h>

#define N_TOK 8192
#define C_DIM 2048
#define F_DIM 5632
#define E_NUM 8
#define BK 64

#define BM 256
#define MAXT 72                      // sum ceil(cnt_e/256) <= 16384/256 + 8 = 72
#define BN1 128
#define GRID1 (MAXT * (F_DIM/BN1))   // 72*44 = 3168, /8 = 396
#define BN2 256
#define KSPLIT 2
#define GRID2 (MAXT * (C_DIM/BN2) * KSPLIT)  // 72*8*2 = 1152, /8 = 144
#define NT1 (C_DIM/BK)               // 32
#define NT2H (F_DIM/BK/KSPLIT)       // 44 k-steps per half
#define KHALF (F_DIM/KSPLIT)         // 2816

typedef __attribute__((ext_vector_type(8))) short bf16x8;
typedef __attribute__((ext_vector_type(4))) float f32x4;

typedef const void __attribute__((address_space(1)))* gas1;
typedef void __attribute__((address_space(3)))* las3;

__device__ __forceinline__ unsigned short f2bf(float f){
  union { float f; unsigned u; } v; v.f = f;
  unsigned r = v.u + 0x7FFFu + ((v.u >> 16) & 1u);   // RNE
  return (unsigned short)(r >> 16);
}

__device__ __forceinline__ void glds16(const unsigned short* g, unsigned short* l){
  __builtin_amdgcn_global_load_lds((gas1)g, (las3)l, 16, 0, 0);
}

#define MFMA_BF16 __builtin_amdgcn_mfma_f32_16x16x32_bf16

// ------- weight convert + transpose (W1 & W3 in one launch): [R][Cc] fp32 -> [Cc][R] bf16 -------
__global__ void k_tcvt_w(const float* __restrict__ inA, const float* __restrict__ inB,
                         unsigned short* __restrict__ out, int R, int Cc){
  __shared__ float t[64][65];
  int z = blockIdx.z;                          // 0..15: z<8 -> W1 slab, z>=8 -> W3 slab
  const float* in = (z < 8 ? inA : inB) + (size_t)(z & 7) * R * Cc;
  out += (size_t)z * R * Cc;                   // wb1 and wb3 contiguous in ws
  int c0 = blockIdx.x * 64, r0 = blockIdx.y * 64;
  int tx = threadIdx.x, ty = threadIdx.y;      // 64 x 4
  #pragma unroll
  for (int i = 0; i < 16; ++i){
    int r = ty + i*4;
    t[r][tx] = in[(size_t)(r0 + r) * Cc + c0 + tx];
  }
  __syncthreads();
  #pragma unroll
  for (int i = 0; i < 16; ++i){
    int cr = ty + i*4;
    out[(size_t)(c0 + cr) * R + r0 + tx] = f2bf(t[tx][cr]);
  }
}

// ---------------- router (+ fused x fp32->bf16 conversion) ----------------
__global__ void k_router(const float* __restrict__ x, const float* __restrict__ Wg,
                         int* __restrict__ cnt, int* __restrict__ list, float* __restrict__ p_slot,
                         unsigned short* __restrict__ xb)
{
  int wid = threadIdx.x >> 6, lane = threadIdx.x & 63;
  int n = blockIdx.x * 4 + wid;                 // one wave per token
  int e = lane >> 3, sub = lane & 7;
  const float* xr = x + (size_t)n * C_DIM;
  float acc = 0.f;
  for (int i0 = sub*4; i0 < C_DIM; i0 += 32){
    float4 v = *(const float4*)&xr[i0];
    acc += v.x * Wg[(i0  )*E_NUM + e];
    acc += v.y * Wg[(i0+1)*E_NUM + e];
    acc += v.z * Wg[(i0+2)*E_NUM + e];
    acc += v.w * Wg[(i0+3)*E_NUM + e];
  }
  acc += __shfl_xor(acc, 1);
  acc += __shfl_xor(acc, 2);
  acc += __shfl_xor(acc, 4);
  float lg[E_NUM];
  #pragma unroll
  for (int j = 0; j < E_NUM; ++j) lg[j] = __shfl(acc, j*8);
  // fused row conversion (row is hot in L1/L2 from the dot product above)
  unsigned short* xbr = xb + (size_t)n * C_DIM;
  #pragma unroll
  for (int i0 = lane*4; i0 < C_DIM; i0 += 256){
    float4 v = *(const float4*)&xr[i0];
    ushort4 u; u.x = f2bf(v.x); u.y = f2bf(v.y); u.z = f2bf(v.z); u.w = f2bf(v.w);
    *(ushort4*)&xbr[i0] = u;
  }
  if (lane == 0){
    int e1 = 0; float m1 = lg[0];
    #pragma unroll
    for (int j = 1; j < E_NUM; ++j) if (lg[j] > m1){ m1 = lg[j]; e1 = j; }
    int e2 = -1; float m2 = -1e30f;
    #pragma unroll
    for (int j = 0; j < E_NUM; ++j) if (j != e1 && lg[j] > m2){ m2 = lg[j]; e2 = j; }
    float p1 = 1.f / (1.f + __expf(m2 - m1));
    float p2 = 1.f - p1;
    int pos1 = atomicAdd(&cnt[e1], 1);
    list[e1*N_TOK + pos1] = n*2;
    p_slot[n*2] = p1;
    int pos2 = atomicAdd(&cnt[e2], 1);
    list[e2*N_TOK + pos2] = n*2 + 1;
    p_slot[n*2 + 1] = p2;
  }
}

// ---------------- prefix / tile table ----------------
__global__ void k_prefix(const int* __restrict__ cnt, int* __restrict__ meta){
  if (threadIdx.x == 0 && blockIdx.x == 0){
    int acc = 0, t = 0;
    for (int e = 0; e < E_NUM; ++e){
      meta[e] = acc; acc += cnt[e];
      int nt = (cnt[e] + BM - 1) / BM;
      for (int i = 0; i < nt; ++i) meta[16 + t++] = (e << 16) | i;
    }
    meta[8] = t;
  }
}

#define PHASE_ENTER() do{ __builtin_amdgcn_sched_barrier(0); __builtin_amdgcn_s_barrier(); \
                          __builtin_amdgcn_s_setprio(1); } while(0)
#define PHASE_EXIT()  do{ __builtin_amdgcn_s_setprio(0); __builtin_amdgcn_sched_barrier(0); \
                          __builtin_amdgcn_s_barrier(); } while(0)

// ---------------- GEMM1: 256x128 dual-B 8-phase, h = silu(x@W1)*(x@W3) ----------------
// (unchanged round-3 anchor)
__global__ __launch_bounds__(512, 2) void k_gemm1(
    const unsigned short* __restrict__ xb,
    const unsigned short* __restrict__ wb1,   // [E][F][C] bf16
    const unsigned short* __restrict__ wb3,   // [E][F][C]
    unsigned short* __restrict__ h,           // [2N+1024][F] bf16
    const int* __restrict__ cnt,
    const int* __restrict__ meta,
    const int* __restrict__ list)
{
  int o = blockIdx.x;
  int w = (o & 7) * (GRID1/8) + (o >> 3);
  int t = w % MAXT;
  int n0 = (w / MAXT) * BN1;
  if (t >= meta[8]) return;
  int info = meta[16 + t];
  int e  = info >> 16;
  int m0 = (info & 0xffff) * BM;
  int count = cnt[e];
  int hbase = meta[e];

  __shared__ __align__(16) unsigned short lds[2*32768];

  int tid = threadIdx.x;
  int lane = tid & 63, wid = tid >> 6;
  int wm = wid >> 1, wn = wid & 1;
  int l15 = lane & 15;
  int xc0 = (lane >> 4) ^ (lane & 7);
  int xc1 = xc0 ^ 4;

  int srow = tid >> 3;
  int swz = ((tid & 7) ^ (srow & 7)) * 8;
  const unsigned short* aP[4];
  #pragma unroll
  for (int u = 0; u < 4; ++u){
    int ts = list[e*N_TOK + m0 + u*64 + srow];
    int tok = (ts >> 1) & (N_TOK - 1);
    aP[u] = xb + (size_t)tok * C_DIM + swz;
  }
  const unsigned short* bP[4];
  #pragma unroll
  for (int u = 0; u < 4; ++u){
    const unsigned short* base = (u < 2) ? wb1 : wb3;
    bP[u] = base + ((size_t)e*F_DIM + n0 + (u & 1)*64 + srow) * C_DIM + swz;
  }
  int ldw = wid * 512;

  #define ST_A(u, kt) glds16(aP[u] + (kt)*BK, &lds[((kt)&1)*32768 + (u)*4096 + ldw])
  #define ST_B(u, kt) glds16(bP[u] + (kt)*BK, &lds[((kt)&1)*32768 + 16384 + (u)*4096 + ldw])

  ST_A(0,0); ST_A(1,0); ST_A(2,0); ST_A(3,0);
  ST_B(0,0); ST_B(1,0); ST_B(2,0); ST_B(3,0);
  ST_A(0,1); ST_A(1,1); ST_A(2,1); ST_A(3,1);
  asm volatile("s_waitcnt vmcnt(4)" ::: "memory");
  __builtin_amdgcn_sched_barrier(0);
  __builtin_amdgcn_s_barrier();

  f32x4 zero = {0.f, 0.f, 0.f, 0.f};
  f32x4 acc1[4][4], acc3[4][4];
  #pragma unroll
  for (int m = 0; m < 4; ++m)
    #pragma unroll
    for (int q = 0; q < 4; ++q){ acc1[m][q] = zero; acc3[m][q] = zero; }

  for (int kt = 0; kt < NT1; ++kt){
    const unsigned short* bufc = &lds[(kt & 1)*32768];
    bf16x8 a[4][2], b1f[2], b3f[2];
    #pragma unroll
    for (int m = 0; m < 4; ++m){
      int row = wm*64 + m*16 + l15;
      a[m][0] = *(const bf16x8*)&bufc[row*64 + xc0*8];
      a[m][1] = *(const bf16x8*)&bufc[row*64 + xc1*8];
    }
    {
      int brow = wn*64 + l15;
      b1f[0] = *(const bf16x8*)&bufc[16384 + brow*64 + xc0*8];
      b1f[1] = *(const bf16x8*)&bufc[16384 + brow*64 + xc1*8];
      b3f[0] = *(const bf16x8*)&bufc[24576 + brow*64 + xc0*8];
      b3f[1] = *(const bf16x8*)&bufc[24576 + brow*64 + xc1*8];
    }
    ST_B(0, kt+1); ST_B(1, kt+1); ST_B(2, kt+1); ST_B(3, kt+1);
    PHASE_ENTER();
    #pragma unroll
    for (int m = 0; m < 4; ++m){
      acc1[m][0] = MFMA_BF16(a[m][0], b1f[0], acc1[m][0], 0, 0, 0);
      acc1[m][0] = MFMA_BF16(a[m][1], b1f[1], acc1[m][0], 0, 0, 0);
      acc3[m][0] = MFMA_BF16(a[m][0], b3f[0], acc3[m][0], 0, 0, 0);
      acc3[m][0] = MFMA_BF16(a[m][1], b3f[1], acc3[m][0], 0, 0, 0);
    }
    PHASE_EXIT();
    #pragma unroll
    for (int q = 1; q < 4; ++q){
      int brow = wn*64 + q*16 + l15;
      b1f[0] = *(const bf16x8*)&bufc[16384 + brow*64 + xc0*8];
      b1f[1] = *(const bf16x8*)&bufc[16384 + brow*64 + xc1*8];
      b3f[0] = *(const bf16x8*)&bufc[24576 + brow*64 + xc0*8];
      b3f[1] = *(const bf16x8*)&bufc[24576 + brow*64 + xc1*8];
      if (q == 1){ ST_A(0, kt+2); ST_A(1, kt+2); }
      if (q == 2){ ST_A(2, kt+2); ST_A(3, kt+2); }
      PHASE_ENTER();
      #pragma unroll
      for (int m = 0; m < 4; ++m){
        acc1[m][q] = MFMA_BF16(a[m][0], b1f[0], acc1[m][q], 0, 0, 0);
        acc1[m][q] = MFMA_BF16(a[m][1], b1f[1], acc1[m][q], 0, 0, 0);
        acc3[m][q] = MFMA_BF16(a[m][0], b3f[0], acc3[m][q], 0, 0, 0);
        acc3[m][q] = MFMA_BF16(a[m][1], b3f[1], acc3[m][q], 0, 0, 0);
      }
      __builtin_amdgcn_s_setprio(0);
      if (q == 3) asm volatile("s_waitcnt vmcnt(4)" ::: "memory");
      __builtin_amdgcn_sched_barrier(0);
      __builtin_amdgcn_s_barrier();
    }
  }
  asm volatile("s_waitcnt vmcnt(0)" ::: "memory");

  #pragma unroll
  for (int m = 0; m < 4; ++m){
    #pragma unroll
    for (int r = 0; r < 4; ++r){
      int rloc = m0 + wm*64 + m*16 + ((lane >> 4) * 4) + r;
      if (rloc < count){
        unsigned short* hrow = h + (size_t)(hbase + rloc) * F_DIM + n0 + wn*64 + l15;
        #pragma unroll
        for (int q = 0; q < 4; ++q){
          float v1 = acc1[m][q][r];
          float v3 = acc3[m][q][r];
          float hv = (v1 / (1.f + __expf(-v1))) * v3;
          hrow[q*16] = f2bf(hv);
        }
      }
    }
  }
  #undef ST_A
  #undef ST_B
}

// ---------------- GEMM2: 256x256 single-B 8-phase, K-split x2, y += p * (h @ W2t) ----------------
__global__ __launch_bounds__(512, 2) void k_gemm2(
    const unsigned short* __restrict__ h,
    const unsigned short* __restrict__ wb2,   // [E][C][F] bf16
    float* __restrict__ y,                    // [N][C] fp32, pre-zeroed
    const int* __restrict__ cnt,
    const int* __restrict__ meta,
    const int* __restrict__ list,
    const float* __restrict__ p_slot)
{
  int o = blockIdx.x;
  int w = (o & 7) * (GRID2/8) + (o >> 3);
  int ks = w / (GRID2/KSPLIT);                // 0/1: K half
  int r2 = w % (GRID2/KSPLIT);
  int t = r2 % MAXT;
  int n0 = (r2 / MAXT) * BN2;
  if (t >= meta[8]) return;
  int info = meta[16 + t];
  int e  = info >> 16;
  int m0 = (info & 0xffff) * BM;
  int count = cnt[e];
  int hbase = meta[e];

  // [2] x { A[256][64], B[256][64] } = 128 KiB
  __shared__ __align__(16) unsigned short lds[2*32768];

  int tid = threadIdx.x;
  int lane = tid & 63, wid = tid >> 6;
  int wm = wid >> 1, wn = wid & 1;            // 4M x 2N waves, wave tile 64x128
  int l15 = lane & 15;
  int xc0 = (lane >> 4) ^ (lane & 7);
  int xc1 = xc0 ^ 4;

  int srow = tid >> 3;
  int swz = ((tid & 7) ^ (srow & 7)) * 8;
  size_t kb0 = (size_t)ks * KHALF;            // element offset into K dim
  const unsigned short* aP[4];
  #pragma unroll
  for (int u = 0; u < 4; ++u)
    aP[u] = h + (size_t)(hbase + m0 + u*64 + srow) * F_DIM + kb0 + swz;
  const unsigned short* bP[4];
  #pragma unroll
  for (int u = 0; u < 4; ++u)
    bP[u] = wb2 + ((size_t)e*C_DIM + n0 + u*64 + srow) * F_DIM + kb0 + swz;
  int ldw = wid * 512;

  #define ST_A2(u, kt) glds16(aP[u] + (kt)*BK, &lds[((kt)&1)*32768 + (u)*4096 + ldw])
  #define ST_B2(u, kt) glds16(bP[u] + (kt)*BK, &lds[((kt)&1)*32768 + 16384 + (u)*4096 + ldw])

  // prologue: A(0),B(0) [8]; vmcnt(4); A(1),B-U0/U2(1) [6]; vmcnt(6) -> kt0 fully landed
  ST_A2(0,0); ST_A2(1,0); ST_A2(2,0); ST_A2(3,0);
  ST_B2(0,0); ST_B2(1,0); ST_B2(2,0); ST_B2(3,0);
  asm volatile("s_waitcnt vmcnt(4)" ::: "memory");
  ST_A2(0,1); ST_A2(1,1); ST_A2(2,1); ST_A2(3,1);
  ST_B2(0,1); ST_B2(2,1);
  asm volatile("s_waitcnt vmcnt(6)" ::: "memory");
  __builtin_amdgcn_sched_barrier(0);
  __builtin_amdgcn_s_barrier();

  f32x4 zero = {0.f, 0.f, 0.f, 0.f};
  f32x4 acc[4][8];
  #pragma unroll
  for (int m = 0; m < 4; ++m)
    #pragma unroll
    for (int nf = 0; nf < 8; ++nf) acc[m][nf] = zero;

  for (int kt = 0; kt < NT2H; ++kt){
    const unsigned short* bufc = &lds[(kt & 1)*32768];
    bf16x8 a[4][2], bf[2][2];
    // ---- phase 0: all A-frags + B-frags 0,1; stage B-U1,U3(kt+1) ----
    #pragma unroll
    for (int m = 0; m < 4; ++m){
      int row = wm*64 + m*16 + l15;
      a[m][0] = *(const bf16x8*)&bufc[row*64 + xc0*8];
      a[m][1] = *(const bf16x8*)&bufc[row*64 + xc1*8];
    }
    #pragma unroll
    for (int j = 0; j < 2; ++j){
      int brow = wn*128 + j*16 + l15;
      bf[j][0] = *(const bf16x8*)&bufc[16384 + brow*64 + xc0*8];
      bf[j][1] = *(const bf16x8*)&bufc[16384 + brow*64 + xc1*8];
    }
    ST_B2(1, kt+1); ST_B2(3, kt+1);
    PHASE_ENTER();
    #pragma unroll
    for (int m = 0; m < 4; ++m)
      #pragma unroll
      for (int j = 0; j < 2; ++j){
        acc[m][j] = MFMA_BF16(a[m][0], bf[j][0], acc[m][j], 0, 0, 0);
        acc[m][j] = MFMA_BF16(a[m][1], bf[j][1], acc[m][j], 0, 0, 0);
      }
    PHASE_EXIT();
    // ---- phases 1..3 ----
    #pragma unroll
    for (int q = 1; q < 4; ++q){
      #pragma unroll
      for (int j = 0; j < 2; ++j){
        int brow = wn*128 + (q*2 + j)*16 + l15;
        bf[j][0] = *(const bf16x8*)&bufc[16384 + brow*64 + xc0*8];
        bf[j][1] = *(const bf16x8*)&bufc[16384 + brow*64 + xc1*8];
      }
      if (q == 1){ ST_A2(0, kt+2); ST_A2(1, kt+2); }
      if (q == 2){ ST_A2(2, kt+2); ST_A2(3, kt+2); }
      if (q == 3){ ST_B2(0, kt+2); ST_B2(2, kt+2); }
      PHASE_ENTER();
      #pragma unroll
      for (int m = 0; m < 4; ++m)
        #pragma unroll
        for (int j = 0; j < 2; ++j){
          acc[m][q*2+j] = MFMA_BF16(a[m][0], bf[j][0], acc[m][q*2+j], 0, 0, 0);
          acc[m][q*2+j] = MFMA_BF16(a[m][1], bf[j][1], acc[m][q*2+j], 0, 0, 0);
        }
      __builtin_amdgcn_s_setprio(0);
      if (q == 3) asm volatile("s_waitcnt vmcnt(6)" ::: "memory");
      __builtin_amdgcn_sched_barrier(0);
      __builtin_amdgcn_s_barrier();
    }
  }
  asm volatile("s_waitcnt vmcnt(0)" ::: "memory");

  // epilogue: commutative fp32 atomic adds per y element from exact 0
  #pragma unroll
  for (int m = 0; m < 4; ++m){
    #pragma unroll
    for (int r = 0; r < 4; ++r){
      int rloc = m0 + wm*64 + m*16 + ((lane >> 4) * 4) + r;
      if (rloc < count){
        int ts = list[e*N_TOK + rloc];
        float p = p_slot[ts];
        int tok = ts >> 1;
        float* yr = y + (size_t)tok * C_DIM + n0 + wn*128 + l15;
        #pragma unroll
        for (int nf = 0; nf < 8; ++nf)
          atomicAdd(&yr[nf*16], p * acc[m][nf][r]);
      }
    }
  }
  #undef ST_A2
  #undef ST_B2
}

extern "C" void kernel_launch(void* const* d_in, const int* in_sizes, int n_in,
                              void* d_out, int out_size, void* d_ws, size_t ws_size,
                              hipStream_t stream)
{
  const float* x  = (const float*)d_in[0];
  const float* Wg = (const float*)d_in[1];
  const float* W1 = (const float*)d_in[2];
  const float* W3 = (const float*)d_in[3];
  const float* W2 = (const float*)d_in[4];
  float* y = (float*)d_out;
  (void)in_sizes; (void)n_in; (void)out_size; (void)ws_size;

  char* ws = (char*)d_ws;
  size_t o = 0;
  auto alloc = [&](size_t bytes)->char* {
    char* p = ws + o;
    o = (o + bytes + 255) & ~(size_t)255;
    return p;
  };
  int*    cnt    = (int*)  alloc(E_NUM * 4);
  int*    meta   = (int*)  alloc(160 * 4);
  float*  p_slot = (float*)alloc((size_t)2*N_TOK * 4);
  int*    list   = (int*)  alloc((size_t)E_NUM*N_TOK * 4);
  unsigned short* xb  = (unsigned short*)alloc((size_t)N_TOK*C_DIM * 2);
  unsigned short* wb1 = (unsigned short*)alloc((size_t)E_NUM*C_DIM*F_DIM * 2);
  unsigned short* wb3 = (unsigned short*)alloc((size_t)E_NUM*C_DIM*F_DIM * 2);  // contiguous after wb1
  unsigned short* wb2 = (unsigned short*)alloc((size_t)E_NUM*C_DIM*F_DIM * 2);
  unsigned short* h   = (unsigned short*)alloc((size_t)(2*N_TOK + 1024)*F_DIM * 2);
  (void)wb3;

  hipMemsetAsync(cnt, 0, E_NUM * 4, stream);
  hipMemsetAsync(y, 0, (size_t)N_TOK * C_DIM * 4, stream);
  k_router<<<N_TOK/4, 256, 0, stream>>>(x, Wg, cnt, list, p_slot, xb);
  k_prefix<<<1, 64, 0, stream>>>(cnt, meta);
  // W1,W3: [E][C][F] -> [E][F][C] bf16, single launch (out slabs contiguous: wb1 then wb3)
  k_tcvt_w<<<dim3(F_DIM/64, C_DIM/64, 2*E_NUM), dim3(64,4), 0, stream>>>(W1, W3, wb1, C_DIM, F_DIM);
  // W2: [E][F][C] -> [E][C][F] bf16
  k_tcvt_w<<<dim3(C_DIM/64, F_DIM/64, E_NUM), dim3(64,4), 0, stream>>>(W2, W2, wb2, F_DIM, C_DIM);
  k_gemm1<<<GRID1, 512, 0, stream>>>(xb, wb1, wb3, h, cnt, meta, list);
  k_gemm2<<<GRID2, 512, 0, stream>>>(h, wb2, y, cnt, meta, list, p_slot);
}